// Round 1
// baseline (60.966 us; speedup 1.0000x reference)
//
#include <hip/hip_runtime.h>
#include <math.h>

#define HWSZ 784      // 28*28
#define NCH  2048
#define NB   16
#define NWIN 1595     // 625 + 529 + 441
#define NF4  196      // 784/4

// ---------------- Kernel 1: per-chunk channel sums ----------------
__global__ __launch_bounds__(256) void k_chan_partial(const float* __restrict__ in,
                                                      float* __restrict__ partial,
                                                      int cc, int nchunks) {
    int chunk = blockIdx.x;
    int b     = blockIdx.y;
    int t     = threadIdx.x;
    if (t >= NF4) return;
    int c0 = chunk * cc;
    const float4* p = reinterpret_cast<const float4*>(in + ((size_t)b * NCH + c0) * HWSZ) + t;
    float4 acc = make_float4(0.f, 0.f, 0.f, 0.f);
#pragma unroll 4
    for (int c = 0; c < cc; ++c) {
        float4 v = p[(size_t)c * NF4];
        acc.x += v.x; acc.y += v.y; acc.z += v.z; acc.w += v.w;
    }
    reinterpret_cast<float4*>(partial + ((size_t)b * nchunks + chunk) * HWSZ)[t] = acc;
}

// ---------------- Kernel 2: reduce partials -> x (16 x 784) ----------------
__global__ __launch_bounds__(256) void k_chan_reduce(const float* __restrict__ partial,
                                                     float* __restrict__ x, int nchunks) {
    int b = blockIdx.x;
    int t = threadIdx.x;
    if (t >= NF4) return;
    float4 acc = make_float4(0.f, 0.f, 0.f, 0.f);
    for (int ch = 0; ch < nchunks; ++ch) {
        float4 v = reinterpret_cast<const float4*>(partial + ((size_t)b * nchunks + ch) * HWSZ)[t];
        acc.x += v.x; acc.y += v.y; acc.z += v.z; acc.w += v.w;
    }
    reinterpret_cast<float4*>(x + (size_t)b * HWSZ)[t] = acc;
}

// ---------------- Kernel 3: pooled window scores ----------------
__global__ __launch_bounds__(256) void k_pool(const float* __restrict__ x,
                                              float* __restrict__ scores_ws,
                                              float* __restrict__ out_win) {
    __shared__ float xs[HWSZ];
    int b = blockIdx.x;
    int t = threadIdx.x;
    for (int i = t; i < HWSZ; i += 256) xs[i] = x[(size_t)b * HWSZ + i];
    __syncthreads();
    for (int w = t; w < NWIN; w += 256) {
        int k, n, base;
        if (w < 625)       { k = 4; n = 25; base = 0;    }
        else if (w < 1154) { k = 6; n = 23; base = 625;  }
        else               { k = 8; n = 21; base = 1154; }
        int loc = w - base;
        int i = loc / n, j = loc % n;
        float s = 0.f;
        for (int di = 0; di < k; ++di) {
            const float* row = xs + (i + di) * 28 + j;
            for (int dj = 0; dj < k; ++dj) s += row[dj];
        }
        s /= (float)(k * k);
        scores_ws[(size_t)b * NWIN + w] = s;
        out_win[(size_t)b * NWIN + w]   = s;
    }
}

// ---------------- Kernel 4: NMS per (batch, group) ----------------
__global__ __launch_bounds__(256) void k_nms(const float* __restrict__ scores_ws,
                                             float* __restrict__ out) {
    const int kArr[3]    = {4, 6, 8};
    const int nArr[3]    = {25, 23, 21};
    const int baseArr[3] = {0, 625, 1154};
    const int pickArr[3] = {3, 2, 1};
    const int offArr[3]  = {0, 3, 5};

    int g = blockIdx.x;
    int b = blockIdx.y;
    int t = threadIdx.x;
    int k = kArr[g], n = nArr[g], base = baseArr[g];
    int npick = pickArr[g], off = offArr[g];
    int cnt = n * n;

    __shared__ float sc[625];
    __shared__ unsigned char valid[625];
    __shared__ float rs[256];
    __shared__ int   ri[256];
    __shared__ int   pickBcast;
    __shared__ int   outIdx[3];
    __shared__ float outScore[3];

    for (int w = t; w < cnt; w += 256) {
        sc[w] = scores_ws[(size_t)b * NWIN + base + w];
        valid[w] = 1;
    }
    __syncthreads();

    for (int r = 0; r < npick; ++r) {
        // local argmax: max score, tie -> smallest index (matches stable argsort)
        float bs = -INFINITY;
        int   bi = 1 << 30;
        for (int w = t; w < cnt; w += 256) {
            if (valid[w]) {
                float s = sc[w];
                if (s > bs || (s == bs && w < bi)) { bs = s; bi = w; }
            }
        }
        rs[t] = bs; ri[t] = bi;
        __syncthreads();
        for (int step = 128; step > 0; step >>= 1) {
            if (t < step) {
                float s2 = rs[t + step]; int i2 = ri[t + step];
                if (s2 > rs[t] || (s2 == rs[t] && i2 < ri[t])) { rs[t] = s2; ri[t] = i2; }
            }
            __syncthreads();
        }
        if (t == 0) {
            pickBcast   = ri[0];
            outIdx[r]   = base + ri[0];
            outScore[r] = rs[0];
        }
        __syncthreads();
        int pw = pickBcast;
        int pi = pw / n, pj = pw % n;
        // suppress: IoU > 0.25  <=>  5*inter > 2*k*k  (same-size boxes, exact integer test)
        for (int w = t; w < cnt; w += 256) {
            if (valid[w]) {
                int i = w / n, j = w % n;
                int di = i - pi; if (di < 0) di = -di;
                int dj = j - pj; if (dj < 0) dj = -dj;
                int iw = k - dj, ih = k - di;
                int inter = (iw > 0 && ih > 0) ? iw * ih : 0;
                if (5 * inter > 2 * k * k) valid[w] = 0;
            }
        }
        __syncthreads();
    }

    if (t == 0) {
        for (int r = 0; r < npick; ++r) {
            out[(size_t)b * 6 + off + r]      = (float)outIdx[r];
            out[96 + (size_t)b * 6 + off + r] = outScore[r];
        }
    }
}

extern "C" void kernel_launch(void* const* d_in, const int* in_sizes, int n_in,
                              void* d_out, int out_size, void* d_ws, size_t ws_size,
                              hipStream_t stream) {
    // input order: num_proposals, input_tensor, window_nums_sum, N_list, iou_thresholds, coordinates_cat
    const float* in = (const float*)d_in[1];
    float* out = (float*)d_out;
    float* ws  = (float*)d_ws;

    // ws layout (floats): x[16*784] | scores[16*1595] | partial[16*nchunks*784]
    float* x      = ws;
    float* scores = ws + NB * HWSZ;
    float* part   = ws + NB * HWSZ + NB * NWIN;

    size_t ws_floats = ws_size / 4;
    size_t fixed = (size_t)NB * HWSZ + (size_t)NB * NWIN;
    int nchunks = 64;
    while (nchunks > 1 && fixed + (size_t)NB * nchunks * HWSZ > ws_floats) nchunks >>= 1;
    int cc = NCH / nchunks;

    dim3 g1(nchunks, NB);
    k_chan_partial<<<g1, 256, 0, stream>>>(in, part, cc, nchunks);
    k_chan_reduce<<<NB, 256, 0, stream>>>(part, x, nchunks);
    k_pool<<<NB, 256, 0, stream>>>(x, scores, out + 192);
    dim3 g4(3, NB);
    k_nms<<<g4, 256, 0, stream>>>(scores, out);
}

// Round 2
// 46.667 us; speedup vs baseline: 1.3064x; 1.3064x over previous
//
#include <hip/hip_runtime.h>
#include <math.h>

#define HWSZ 784      // 28*28
#define NCH  2048
#define NB   16
#define NWIN 1595     // 625 + 529 + 441
#define NF4  196      // 784/4

// ---------------- Kernel 1: per-chunk channel sums ----------------
__global__ __launch_bounds__(256) void k_chan_partial(const float* __restrict__ in,
                                                      float* __restrict__ partial,
                                                      int cc, int nchunks) {
    int chunk = blockIdx.x;
    int b     = blockIdx.y;
    int t     = threadIdx.x;
    if (t >= NF4) return;
    const float4* p = reinterpret_cast<const float4*>(in + ((size_t)b * NCH + (size_t)chunk * cc) * HWSZ) + t;
    float4 acc = make_float4(0.f, 0.f, 0.f, 0.f);
#pragma unroll 8
    for (int c = 0; c < cc; ++c) {
        float4 v = p[(size_t)c * NF4];
        acc.x += v.x; acc.y += v.y; acc.z += v.z; acc.w += v.w;
    }
    reinterpret_cast<float4*>(partial + ((size_t)b * nchunks + chunk) * HWSZ)[t] = acc;
}

// ---------------- Kernel 2: fused reduce + pool + NMS (one block per batch) ----------------
__global__ __launch_bounds__(256) void k_fused(const float* __restrict__ partial,
                                               int nchunks,
                                               float* __restrict__ out) {
    __shared__ float xs[HWSZ];
    __shared__ float sc[NWIN];
    int b = blockIdx.x;
    int t = threadIdx.x;

    // --- reduce partials -> xs ---
    if (t < NF4) {
        float4 acc = make_float4(0.f, 0.f, 0.f, 0.f);
        for (int ch = 0; ch < nchunks; ++ch) {
            float4 v = reinterpret_cast<const float4*>(partial + ((size_t)b * nchunks + ch) * HWSZ)[t];
            acc.x += v.x; acc.y += v.y; acc.z += v.z; acc.w += v.w;
        }
        reinterpret_cast<float4*>(xs)[t] = acc;
    }
    __syncthreads();

    // --- pool -> sc (LDS) + window_scores (global) ---
    float* out_win = out + 192;
    for (int w = t; w < NWIN; w += 256) {
        int k, n, base;
        if (w < 625)       { k = 4; n = 25; base = 0;    }
        else if (w < 1154) { k = 6; n = 23; base = 625;  }
        else               { k = 8; n = 21; base = 1154; }
        int loc = w - base;
        int i = loc / n, j = loc % n;
        float s = 0.f;
        for (int di = 0; di < k; ++di) {
            const float* row = xs + (i + di) * 28 + j;
            for (int dj = 0; dj < k; ++dj) s += row[dj];
        }
        s /= (float)(k * k);
        sc[w] = s;
        out_win[(size_t)b * NWIN + w] = s;
    }
    __syncthreads();

    // --- NMS: wave g handles group g, entirely in registers ---
    int wave = t >> 6, lane = t & 63;
    if (wave < 3) {
        const int kArr[3]    = {4, 6, 8};
        const int nArr[3]    = {25, 23, 21};
        const int baseArr[3] = {0, 625, 1154};
        const int pickArr[3] = {3, 2, 1};
        const int offArr[3]  = {0, 3, 5};
        int k = kArr[wave], n = nArr[wave], base = baseArr[wave];
        int npick = pickArr[wave], off = offArr[wave];
        int cnt = n * n;           // <= 625 -> <= 10 slots/lane
        int kk2 = 2 * k * k;

        float s[10];
#pragma unroll
        for (int j = 0; j < 10; ++j) {
            int w = lane + 64 * j;
            s[j] = (w < cnt) ? sc[base + w] : -INFINITY;
        }

        for (int r = 0; r < npick; ++r) {
            // lane-local argmax (max score, tie -> smallest window index)
            float bs = -INFINITY;
            int   bi = 1 << 30;
#pragma unroll
            for (int j = 0; j < 10; ++j) {
                int w = lane + 64 * j;
                float v = s[j];
                if (v > bs || (v == bs && w < bi)) { bs = v; bi = w; }
            }
            // wave butterfly reduce
#pragma unroll
            for (int m = 1; m < 64; m <<= 1) {
                float os = __shfl_xor(bs, m);
                int   oi = __shfl_xor(bi, m);
                if (os > bs || (os == bs && oi < bi)) { bs = os; bi = oi; }
            }
            if (lane == 0) {
                out[(size_t)b * 6 + off + r]      = (float)(base + bi);
                out[96 + (size_t)b * 6 + off + r] = bs;
            }
            // suppress: IoU > 0.25  <=>  5*inter > 2*k*k (same-size boxes, exact int test)
            int pi = bi / n, pj = bi % n;
#pragma unroll
            for (int j = 0; j < 10; ++j) {
                int w = lane + 64 * j;
                int i  = w / n, jj = w % n;
                int di = i - pi;  if (di < 0) di = -di;
                int dj = jj - pj; if (dj < 0) dj = -dj;
                int iw = k - dj, ih = k - di;
                int inter = (iw > 0 && ih > 0) ? iw * ih : 0;
                if (5 * inter > kk2) s[j] = -INFINITY;
            }
        }
    }
}

extern "C" void kernel_launch(void* const* d_in, const int* in_sizes, int n_in,
                              void* d_out, int out_size, void* d_ws, size_t ws_size,
                              hipStream_t stream) {
    // input order: num_proposals, input_tensor, window_nums_sum, N_list, iou_thresholds, coordinates_cat
    const float* in = (const float*)d_in[1];
    float* out = (float*)d_out;
    float* ws  = (float*)d_ws;

    size_t ws_floats = ws_size / 4;
    int nchunks = 32;
    while (nchunks > 1 && (size_t)NB * nchunks * HWSZ > ws_floats) nchunks >>= 1;
    int cc = NCH / nchunks;

    float* part = ws;

    dim3 g1(nchunks, NB);
    k_chan_partial<<<g1, 256, 0, stream>>>(in, part, cc, nchunks);
    k_fused<<<NB, 256, 0, stream>>>(part, nchunks, out);
}